// Round 2
// baseline (376.176 us; speedup 1.0000x reference)
//
#include <hip/hip_runtime.h>
#include <hip/hip_bf16.h>

#define Bn 2
#define Tn 4096
#define Cn 768
#define Hn 12
#define Dn 64
#define Mn (Bn * Tn)   // 8192
#define PAD 72         // padded LDS row stride (bf16 elems) for attn/transpose

typedef __attribute__((ext_vector_type(8))) short bf16x8;
typedef __attribute__((ext_vector_type(4))) float f32x4;

typedef const __attribute__((address_space(1))) unsigned int* gas_ptr;
typedef __attribute__((address_space(3))) unsigned int* las_ptr;

__device__ __forceinline__ float b2f(unsigned short u) {
    return __uint_as_float(((unsigned int)u) << 16);
}
__device__ __forceinline__ unsigned short f2b(float f) {
    unsigned int x = __float_as_uint(f);
    x += 0x7FFFu + ((x >> 16) & 1u);   // round-to-nearest-even
    return (unsigned short)(x >> 16);
}
// packed f32x2 -> bf16x2 (single VALU op; replaces 2x f2b = ~6 ops)
__device__ __forceinline__ unsigned int cvt_pk_bf16(float lo, float hi) {
    unsigned int r;
    asm("v_cvt_pk_bf16_f32 %0, %1, %2" : "=v"(r) : "v"(lo), "v"(hi));
    return r;
}

// Async global->LDS, 16B/lane. LDS dest = wave-uniform base + lane*16.
__device__ __forceinline__ void async_ld16(const unsigned short* g, unsigned short* l) {
    __builtin_amdgcn_global_load_lds((gas_ptr)(const void*)g, (las_ptr)(void*)l, 16, 0, 0);
}

// ---------------------------------------------------------------------------
// Input dtype detection (fp32 read as bf16 halves shows huge exponents).
// ---------------------------------------------------------------------------
__global__ void detect_k(const unsigned short* __restrict__ W, int* __restrict__ flag) {
    __shared__ int any;
    if (threadIdx.x == 0) any = 0;
    __syncthreads();
    int bad = 0;
    for (int i = threadIdx.x; i < 65536; i += 256) {
        const unsigned int e = (W[i] >> 7) & 0xFFu;
        bad |= (e >= 0x88u) ? 1 : 0;
    }
    if (bad) atomicOr(&any, 1);
    __syncthreads();
    if (threadIdx.x == 0) *flag = any;
}

// Convert x (fp32 or bf16 per flag) -> bf16 flat copy. 8 elems/thread.
__global__ __launch_bounds__(256) void convert_x_k(
    const void* __restrict__ in, unsigned short* __restrict__ out,
    const int* __restrict__ flag)
{
    const size_t i = ((size_t)blockIdx.x * 256 + threadIdx.x) * 8;
    union { int4 v; unsigned short u[8]; } pk;
    if (*flag) {
        const float* p = (const float*)in + i;
        float4 a = *reinterpret_cast<const float4*>(p);
        float4 b = *reinterpret_cast<const float4*>(p + 4);
        float t[8] = {a.x, a.y, a.z, a.w, b.x, b.y, b.z, b.w};
#pragma unroll
        for (int j = 0; j < 8; ++j) pk.u[j] = f2b(t[j]);
    } else {
        pk.v = *reinterpret_cast<const int4*>((const unsigned short*)in + i);
    }
    *reinterpret_cast<int4*>(out + i) = pk.v;
}

// Transpose weight: in[K][N] (fp32 or bf16 per flag) -> out[N][K] bf16. 64x64 tiles.
__global__ __launch_bounds__(256) void transpose_w_k(
    const void* __restrict__ in, unsigned short* __restrict__ out,
    int K, int N, const int* __restrict__ flag)
{
    __shared__ unsigned short Ts[64][PAD];   // [n][k]
    const int tid = threadIdx.x;
    const int kB = blockIdx.y * 64, nB = blockIdx.x * 64;
    const bool f32 = (*flag != 0);
#pragma unroll
    for (int it = 0; it < 2; ++it) {
        const int r = (tid >> 3) + it * 32;   // k-row in tile
        const int c = (tid & 7) * 8;          // n-col chunk
        float t[8];
        if (f32) {
            const float* p = (const float*)in + (size_t)(kB + r) * N + nB + c;
            float4 a = *reinterpret_cast<const float4*>(p);
            float4 b = *reinterpret_cast<const float4*>(p + 4);
            t[0]=a.x;t[1]=a.y;t[2]=a.z;t[3]=a.w;t[4]=b.x;t[5]=b.y;t[6]=b.z;t[7]=b.w;
        } else {
            int4 v = *reinterpret_cast<const int4*>((const unsigned short*)in + (size_t)(kB + r) * N + nB + c);
            const unsigned short* u = reinterpret_cast<const unsigned short*>(&v);
#pragma unroll
            for (int j = 0; j < 8; ++j) t[j] = b2f(u[j]);
        }
#pragma unroll
        for (int j = 0; j < 8; ++j) Ts[c + j][r] = f2b(t[j]);
    }
    __syncthreads();
#pragma unroll
    for (int it = 0; it < 2; ++it) {
        const int n = (tid >> 3) + it * 32;
        const int k = (tid & 7) * 8;
        *reinterpret_cast<int4*>(out + (size_t)(nB + n) * K + kB + k) =
            *reinterpret_cast<const int4*>(&Ts[n][k]);
    }
}

// Transpose V per head: [T][D] -> [D][T], bf16. 64x64 tiles.
__global__ __launch_bounds__(256) void transpose_v_k(
    const unsigned short* __restrict__ Vin, unsigned short* __restrict__ Vt)
{
    __shared__ unsigned short Ts[64][PAD];
    const int tid = threadIdx.x;
    const size_t base = (size_t)blockIdx.y * Tn * Dn;
    const int t0 = blockIdx.x * 64;
#pragma unroll
    for (int it = 0; it < 2; ++it) {
        const int r = (tid >> 3) + it * 32;     // t-row
        const int c = (tid & 7) * 8;            // d chunk
        int4 vv = *reinterpret_cast<const int4*>(Vin + base + (size_t)(t0 + r) * Dn + c);
        const unsigned short* u = reinterpret_cast<const unsigned short*>(&vv);
#pragma unroll
        for (int j = 0; j < 8; ++j) Ts[c + j][r] = u[j];
    }
    __syncthreads();
#pragma unroll
    for (int it = 0; it < 2; ++it) {
        const int d = (tid >> 3) + it * 32;
        const int tc = (tid & 7) * 8;
        *reinterpret_cast<int4*>(Vt + base + (size_t)d * Tn + t0 + tc) =
            *reinterpret_cast<const int4*>(&Ts[d][tc]);
    }
}

// ---------------------------------------------------------------------------
// m97-style MFMA GEMM: C[M,N] = A[M,K]*Bt[N,K]^T, A/Bt bf16, fp32 accum.
// 128x128 tile, BK=64, 4 waves (64x64 quadrant each). Fragment-order LDS
// staging via global_load_lds. EPI==0: row-major store. EPI==1: QKV split.
// ---------------------------------------------------------------------------
template <int EPI>
__global__ __launch_bounds__(256) void gemm_lds(
    const unsigned short* __restrict__ A, const unsigned short* __restrict__ Bt,
    void* __restrict__ Out, unsigned short* __restrict__ Qo,
    unsigned short* __restrict__ Ko, unsigned short* __restrict__ Vo,
    int M, int N, int K, const int* __restrict__ flag)
{
    __shared__ unsigned short As[8192];   // 16 chunks x 512 elems
    __shared__ unsigned short Bs[8192];
    const int tid = threadIdx.x;
    const int w = tid >> 6, l = tid & 63;
    const int l15 = l & 15, l4 = l >> 4;
    const int rowBase = blockIdx.y * 128;
    const int colBase = blockIdx.x * 128;
    const int mq = (w & 1) * 64, nq = (w >> 1) * 64;
    const bool f32 = (*flag != 0);

    const int laneRow = l15, laneK = l4 * 8;

    f32x4 acc[4][4];
#pragma unroll
    for (int i = 0; i < 4; ++i)
#pragma unroll
        for (int j = 0; j < 4; ++j) acc[i][j] = (f32x4){0.f, 0.f, 0.f, 0.f};

    for (int k0 = 0; k0 < K; k0 += 64) {
        __syncthreads();
#pragma unroll
        for (int j = 0; j < 4; ++j) {
            const int c = w * 4 + j;
            const int mt_g = c >> 1, kh = c & 1;
            const size_t ga = (size_t)(rowBase + mt_g * 16 + laneRow) * K + k0 + kh * 32 + laneK;
            const size_t gb = (size_t)(colBase + mt_g * 16 + laneRow) * K + k0 + kh * 32 + laneK;
            async_ld16(A + ga, &As[c * 512]);
            async_ld16(Bt + gb, &Bs[c * 512]);
        }
        __syncthreads();

#pragma unroll
        for (int kh = 0; kh < 2; ++kh) {
            bf16x8 af[4], bf[4];
#pragma unroll
            for (int mt = 0; mt < 4; ++mt)
                af[mt] = *reinterpret_cast<const bf16x8*>(
                    &As[(((mq >> 4) + mt) * 2 + kh) * 512 + l * 8]);
#pragma unroll
            for (int nt = 0; nt < 4; ++nt)
                bf[nt] = *reinterpret_cast<const bf16x8*>(
                    &Bs[(((nq >> 4) + nt) * 2 + kh) * 512 + l * 8]);
#pragma unroll
            for (int mt = 0; mt < 4; ++mt)
#pragma unroll
                for (int nt = 0; nt < 4; ++nt)
                    acc[mt][nt] = __builtin_amdgcn_mfma_f32_16x16x32_bf16(af[mt], bf[nt], acc[mt][nt], 0, 0, 0);
        }
    }

#pragma unroll
    for (int mt = 0; mt < 4; ++mt)
#pragma unroll
        for (int i = 0; i < 4; ++i) {
            const int m = rowBase + mq + mt * 16 + l4 * 4 + i;
#pragma unroll
            for (int nt = 0; nt < 4; ++nt) {
                const int n0 = colBase + nq + nt * 16 + l15;
                if (EPI == 0) {
                    if (f32) ((float*)Out)[(size_t)m * N + n0] = acc[mt][nt][i];
                    else ((unsigned short*)Out)[(size_t)m * N + n0] = f2b(acc[mt][nt][i]);
                } else {
                    const int sec = n0 / 768;
                    const int cc = n0 - sec * 768;
                    const int h = cc >> 6, d = cc & 63;
                    const int b = m >> 12, t = m & 4095;
                    unsigned short* dst = (sec == 0) ? Qo : (sec == 1) ? Ko : Vo;
                    dst[(((size_t)(b * Hn + h) * Tn + t) * Dn) + d] = f2b(acc[mt][nt][i]);
                }
            }
        }
}

// ---------------------------------------------------------------------------
// Fallback QKV GEMM (verified): VGPR staging with inline fp32->bf16.
// ---------------------------------------------------------------------------
__global__ __launch_bounds__(256) void gemm_qkv_fb(
    const void* __restrict__ A, const unsigned short* __restrict__ Bt,
    unsigned short* __restrict__ Qo, unsigned short* __restrict__ Ko,
    unsigned short* __restrict__ Vo, int M, int N, int K,
    const int* __restrict__ flag)
{
    __shared__ unsigned short As[128 * PAD];
    __shared__ unsigned short Bs[128 * PAD];
    const int tid = threadIdx.x;
    const int w = tid >> 6, l = tid & 63;
    const int l15 = l & 15, l4 = l >> 4;
    const int rowBase = blockIdx.y * 128;
    const int colBase = blockIdx.x * 128;
    const int mq = (w & 1) * 64, nq = (w >> 1) * 64;
    const bool af32 = (*flag != 0);

    f32x4 acc[4][4];
#pragma unroll
    for (int i = 0; i < 4; ++i)
#pragma unroll
        for (int j = 0; j < 4; ++j) acc[i][j] = (f32x4){0.f, 0.f, 0.f, 0.f};

    for (int k0 = 0; k0 < K; k0 += 64) {
        __syncthreads();
#pragma unroll
        for (int it = 0; it < 4; ++it) {
            const int s = tid + it * 256;
            const int r = s >> 3, c = (s & 7) * 8;
            union { int4 v; unsigned short u[8]; } pk;
            if (af32) {
                const float* p = (const float*)A + (size_t)(rowBase + r) * K + k0 + c;
                float4 a = *reinterpret_cast<const float4*>(p);
                float4 b = *reinterpret_cast<const float4*>(p + 4);
                float t[8] = {a.x, a.y, a.z, a.w, b.x, b.y, b.z, b.w};
#pragma unroll
                for (int j = 0; j < 8; ++j) pk.u[j] = f2b(t[j]);
            } else {
                pk.v = *reinterpret_cast<const int4*>(
                    (const unsigned short*)A + (size_t)(rowBase + r) * K + k0 + c);
            }
            *reinterpret_cast<int4*>(&As[r * PAD + c]) = pk.v;
            *reinterpret_cast<int4*>(&Bs[r * PAD + c]) =
                *reinterpret_cast<const int4*>(Bt + (size_t)(colBase + r) * K + k0 + c);
        }
        __syncthreads();
#pragma unroll
        for (int kk = 0; kk < 64; kk += 32) {
            bf16x8 af[4], bf[4];
#pragma unroll
            for (int mt = 0; mt < 4; ++mt)
                af[mt] = *reinterpret_cast<const bf16x8*>(&As[(mq + mt * 16 + l15) * PAD + kk + l4 * 8]);
#pragma unroll
            for (int nt = 0; nt < 4; ++nt)
                bf[nt] = *reinterpret_cast<const bf16x8*>(&Bs[(nq + nt * 16 + l15) * PAD + kk + l4 * 8]);
#pragma unroll
            for (int mt = 0; mt < 4; ++mt)
#pragma unroll
                for (int nt = 0; nt < 4; ++nt)
                    acc[mt][nt] = __builtin_amdgcn_mfma_f32_16x16x32_bf16(af[mt], bf[nt], acc[mt][nt], 0, 0, 0);
        }
    }

#pragma unroll
    for (int mt = 0; mt < 4; ++mt)
#pragma unroll
        for (int i = 0; i < 4; ++i) {
            const int m = rowBase + mq + mt * 16 + l4 * 4 + i;
#pragma unroll
            for (int nt = 0; nt < 4; ++nt) {
                const int n0 = colBase + nq + nt * 16 + l15;
                const int sec = n0 / 768;
                const int cc = n0 - sec * 768;
                const int h = cc >> 6, d = cc & 63;
                const int b = m >> 12, t = m & 4095;
                unsigned short* dst = (sec == 0) ? Qo : (sec == 1) ? Ko : Vo;
                dst[(((size_t)(b * Hn + h) * Tn + t) * Dn) + d] = f2b(acc[mt][nt][i]);
            }
        }
}

// ---------------------------------------------------------------------------
// MFMA flash attention v2: folded-pair balance + swapped QK^T + DMA staging.
//
// - K and V^T staged via global_load_lds in MFMA-fragment-chunk order
//   (zero LDS-write instructions, conflict-free ds_read_b128 fragments).
//   Requires V pre-transposed to [B,H,D,T] (transpose_v_k).
// - Swapped QK^T: z = mfma(K_frag, Q_frag) -> C holds P^T: lane (l15,l4)
//   owns q=l15 and 16 contiguous keys tt*16+l4*4+i. P packs in-lane via
//   v_cvt_pk_bf16_f32 (8 ops) + 4 ds_write_b64 (wave-private strip),
//   replacing 16 f2b + 16 ds_write_b16.
// - l_i: one scalar per lane (q=l15), reduced over l4 groups at the end.
// ---------------------------------------------------------------------------
__global__ __launch_bounds__(256, 4) void attn_mfma2(
    const unsigned short* __restrict__ Q, const unsigned short* __restrict__ K,
    const unsigned short* __restrict__ Vt, unsigned short* __restrict__ Y)
{
    __shared__ unsigned short Ks[8 * 512];   // chunk (tt,kh): 16 keys x 32 d
    __shared__ unsigned short Vs[8 * 512];   // chunk (dt,kh): 16 d x 32 keys
    __shared__ unsigned short Ps[64 * PAD];  // [q-local][key]

    const int tid = threadIdx.x;
    const int w = tid >> 6, l = tid & 63;    // 4 waves x 16 q-rows
    const int l15 = l & 15, l4 = l >> 4;
    const int bh = blockIdx.y;
    const size_t base = (size_t)bh * Tn * Dn;   // same size for K ([T][D]) and Vt ([D][T])
    const float sc = 0.125f * 1.44269504088896f;   // D^-0.5 * log2(e)
    const int b = bh / Hn, h = bh - b * Hn;

    for (int half = 0; half < 2; ++half) {
        const int t = half ? (int)blockIdx.x : (63 - (int)blockIdx.x);  // heavy first
        const int q0 = t * 64;
        const int qrow = q0 + w * 16 + l15;    // this lane's q (swapped layout)

        bf16x8 aq[2];
#pragma unroll
        for (int kh = 0; kh < 2; ++kh)
            aq[kh] = *reinterpret_cast<const bf16x8*>(
                Q + base + (size_t)qrow * Dn + kh * 32 + l4 * 8);

        f32x4 o[4];
#pragma unroll
        for (int dt = 0; dt < 4; ++dt) o[dt] = (f32x4){0.f, 0.f, 0.f, 0.f};
        float lsum = 0.f;

        const int kend = q0 + 64;
        for (int k0 = 0; k0 < kend; k0 += 64) {
            __syncthreads();   // prior stage's fragment reads complete
            // wave w DMAs chunks {2w, 2w+1} of K and V^T
#pragma unroll
            for (int j = 0; j < 2; ++j) {
                const int c = w * 2 + j;
                const int sub = c >> 1, kh = c & 1;
                async_ld16(K + base + (size_t)(k0 + sub * 16 + l15) * Dn + kh * 32 + l4 * 8,
                           &Ks[c * 512]);
                async_ld16(Vt + base + (size_t)(sub * 16 + l15) * Tn + k0 + kh * 32 + l4 * 8,
                           &Vs[c * 512]);
            }
            __syncthreads();   // drains vmcnt: DMA complete

            // S^T = K Q^T: C[col=q(l15)][row=key(l4*4+i)] per key-subtile tt
            f32x4 sfr[4];
#pragma unroll
            for (int tt = 0; tt < 4; ++tt) {
                bf16x8 ak0 = *reinterpret_cast<const bf16x8*>(&Ks[(tt * 2 + 0) * 512 + l * 8]);
                bf16x8 ak1 = *reinterpret_cast<const bf16x8*>(&Ks[(tt * 2 + 1) * 512 + l * 8]);
                f32x4 z = (f32x4){0.f, 0.f, 0.f, 0.f};
                z = __builtin_amdgcn_mfma_f32_16x16x32_bf16(ak0, aq[0], z, 0, 0, 0);
                z = __builtin_amdgcn_mfma_f32_16x16x32_bf16(ak1, aq[1], z, 0, 0, 0);
                sfr[tt] = z;
            }

            // p = exp2(s*sc), causal mask only on the last stage
            const bool need_mask = (k0 + 63 > q0);
            float p[4][4];
#pragma unroll
            for (int tt = 0; tt < 4; ++tt)
#pragma unroll
                for (int i = 0; i < 4; ++i) {
                    float s = sfr[tt][i] * sc;
                    if (need_mask && (k0 + tt * 16 + l4 * 4 + i > qrow)) s = -1e30f;
                    const float e = exp2f(s);
                    p[tt][i] = e;
                    lsum += e;
                }

            // pack P (keys contiguous in-lane) and write wave-private strip
#pragma unroll
            for (int tt = 0; tt < 4; ++tt) {
                uint2 pw;
                pw.x = cvt_pk_bf16(p[tt][0], p[tt][1]);
                pw.y = cvt_pk_bf16(p[tt][2], p[tt][3]);
                *reinterpret_cast<uint2*>(&Ps[(w * 16 + l15) * PAD + tt * 16 + l4 * 4]) = pw;
            }

            bf16x8 ap0 = *reinterpret_cast<const bf16x8*>(&Ps[(w * 16 + l15) * PAD + l4 * 8]);
            bf16x8 ap1 = *reinterpret_cast<const bf16x8*>(&Ps[(w * 16 + l15) * PAD + 32 + l4 * 8]);
#pragma unroll
            for (int dt = 0; dt < 4; ++dt) {
                bf16x8 bv0 = *reinterpret_cast<const bf16x8*>(&Vs[(dt * 2 + 0) * 512 + l * 8]);
                bf16x8 bv1 = *reinterpret_cast<const bf16x8*>(&Vs[(dt * 2 + 1) * 512 + l * 8]);
                o[dt] = __builtin_amdgcn_mfma_f32_16x16x32_bf16(ap0, bv0, o[dt], 0, 0, 0);
                o[dt] = __builtin_amdgcn_mfma_f32_16x16x32_bf16(ap1, bv1, o[dt], 0, 0, 0);
            }
        }

        // reduce lsum across the 4 l4-groups sharing q=l15
        lsum += __shfl_xor(lsum, 16);
        lsum += __shfl_xor(lsum, 32);

#pragma unroll
        for (int i = 0; i < 4; ++i) {
            // output row q-local = l4*4+i; its lsum lives at lane l15 == l4*4+i
            const float lv = __shfl(lsum, (l & 48) + (l4 * 4 + i));
            const float inv = 1.0f / lv;
            const int row = q0 + w * 16 + l4 * 4 + i;
#pragma unroll
            for (int dt = 0; dt < 4; ++dt)
                Y[((size_t)(b * Tn + row)) * Cn + h * 64 + dt * 16 + l15] = f2b(o[dt][i] * inv);
        }
    }
}

// ---------------------------------------------------------------------------
// Fallback attention (round-1 verified, no V^T buffer needed).
// ---------------------------------------------------------------------------
__global__ __launch_bounds__(256, 3) void attn_mfma_fb(
    const unsigned short* __restrict__ Q, const unsigned short* __restrict__ K,
    const unsigned short* __restrict__ V, unsigned short* __restrict__ Y)
{
    __shared__ unsigned short Ks[96 * PAD];
    __shared__ unsigned short Vtl[96 * PAD];
    __shared__ unsigned short Ps[96 * PAD];

    const int tid = threadIdx.x;
    const int w = tid >> 6, l = tid & 63;
    const int l15 = l & 15, l4 = l >> 4;
    const int bh = blockIdx.y;
    const size_t base = (size_t)bh * Tn * Dn;
    const float sc = 0.125f * 1.44269504088896f;
    const int b = bh / Hn, h = bh - b * Hn;

    for (int half = 0; half < 2; ++half) {
        const int t = half ? (int)blockIdx.x : (63 - (int)blockIdx.x);
        const int q0 = t * 64;

        bf16x8 aq[2];
#pragma unroll
        for (int kh = 0; kh < 2; ++kh)
            aq[kh] = *reinterpret_cast<const bf16x8*>(
                Q + base + (size_t)(q0 + w * 16 + l15) * Dn + kh * 32 + l4 * 8);

        f32x4 o[4];
#pragma unroll
        for (int dt = 0; dt < 4; ++dt) o[dt] = (f32x4){0.f, 0.f, 0.f, 0.f};
        float l_i[4] = {0.f, 0.f, 0.f, 0.f};

        const int kend = q0 + 64;
        for (int k0 = 0; k0 < kend; k0 += 64) {
            __syncthreads();
#pragma unroll
            for (int it = 0; it < 2; ++it) {
                const int s = tid + it * 256;
                const int r = s >> 3, c = (s & 7) * 8;
                *reinterpret_cast<int4*>(&Ks[r * PAD + c]) =
                    *reinterpret_cast<const int4*>(K + base + (size_t)(k0 + r) * Dn + c);
            }
#pragma unroll
            for (int it = 0; it < 2; ++it) {
                const int r = tid & 63, d0 = (tid >> 6) * 8 + it * 32;
                int4 vv = *reinterpret_cast<const int4*>(V + base + (size_t)(k0 + r) * Dn + d0);
                const unsigned short* vu = reinterpret_cast<const unsigned short*>(&vv);
#pragma unroll
                for (int j = 0; j < 8; ++j) Vtl[(d0 + j) * PAD + r] = vu[j];
            }
            __syncthreads();

            f32x4 sfr[4];
#pragma unroll
            for (int tt = 0; tt < 4; ++tt) {
                bf16x8 bk0 = *reinterpret_cast<const bf16x8*>(&Ks[(tt * 16 + l15) * PAD + l4 * 8]);
                bf16x8 bk1 = *reinterpret_cast<const bf16x8*>(&Ks[(tt * 16 + l15) * PAD + 32 + l4 * 8]);
                f32x4 z = (f32x4){0.f, 0.f, 0.f, 0.f};
                z = __builtin_amdgcn_mfma_f32_16x16x32_bf16(aq[0], bk0, z, 0, 0, 0);
                z = __builtin_amdgcn_mfma_f32_16x16x32_bf16(aq[1], bk1, z, 0, 0, 0);
                sfr[tt] = z;
            }

            const bool need_mask = (k0 + 63 > q0);
            float p[4][4];
#pragma unroll
            for (int tt = 0; tt < 4; ++tt) {
                const int cb = k0 + tt * 16 + l15;
                const int rb = q0 + w * 16 + l4 * 4;
#pragma unroll
                for (int i = 0; i < 4; ++i) {
                    float s = sfr[tt][i] * sc;
                    if (need_mask && (cb > rb + i)) s = -1e30f;
                    const float e = exp2f(s);
                    p[tt][i] = e;
                    l_i[i] += e;
                }
            }

#pragma unroll
            for (int tt = 0; tt < 4; ++tt)
#pragma unroll
                for (int i = 0; i < 4; ++i)
                    Ps[(w * 16 + l4 * 4 + i) * PAD + tt * 16 + l15] = f2b(p[tt][i]);

            bf16x8 ap0 = *reinterpret_cast<const bf16x8*>(&Ps[(w * 16 + l15) * PAD + l4 * 8]);
            bf16x8 ap1 = *reinterpret_cast<const bf16x8*>(&Ps[(w * 16 + l15) * PAD + 32 + l4 * 8]);
#pragma unroll
            for (int dt = 0; dt < 4; ++dt) {
                bf16x8 bv0 = *reinterpret_cast<const bf16x8*>(&Vtl[(dt * 16 + l15) * PAD + l4 * 8]);
                bf16x8 bv1 = *reinterpret_cast<const bf16x8*>(&Vtl[(dt * 16 + l15) * PAD + 32 + l4 * 8]);
                o[dt] = __builtin_amdgcn_mfma_f32_16x16x32_bf16(ap0, bv0, o[dt], 0, 0, 0);
                o[dt] = __builtin_amdgcn_mfma_f32_16x16x32_bf16(ap1, bv1, o[dt], 0, 0, 0);
            }
        }

#pragma unroll
        for (int i = 0; i < 4; ++i)
#pragma unroll
            for (int off = 1; off < 16; off <<= 1) l_i[i] += __shfl_xor(l_i[i], off);

#pragma unroll
        for (int i = 0; i < 4; ++i) {
            const float inv = 1.0f / l_i[i];
            const int row = q0 + w * 16 + l4 * 4 + i;
#pragma unroll
            for (int dt = 0; dt < 4; ++dt)
                Y[((size_t)(b * Tn + row)) * Cn + h * 64 + dt * 16 + l15] = f2b(o[dt][i] * inv);
        }
    }
}

extern "C" void kernel_launch(void* const* d_in, const int* in_sizes, int n_in,
                              void* d_out, int out_size, void* d_ws, size_t ws_size,
                              hipStream_t stream)
{
    const void* x = d_in[0];
    const void* wqkv = d_in[1];
    const void* wproj = d_in[2];
    const size_t HSZ = (size_t)Bn * Hn * Tn * Dn;   // 6291456 elems
    unsigned short* q = (unsigned short*)d_ws;
    unsigned short* k = q + HSZ;
    unsigned short* v = k + HSZ;
    unsigned short* R = v + HSZ;          // wqkvT during QKV gemm, y afterwards
    unsigned short* wqkvT = R;            // [2304][768] = 1769472 elems <= HSZ
    unsigned short* y = R;
    unsigned short* wprojT = q;           // [768][768], reused after attn
    // Big layout adds xb (bf16 copy of x) at 4*HSZ; vt reuses xb after the
    // QKV gemm (both HSZ elems). Need 5*HSZ*2+16 bytes.
    const bool big = ws_size >= (size_t)5 * HSZ * 2 + 16;
    unsigned short* xb = R + HSZ;
    unsigned short* vt = xb;              // V^T [B,H,D,T], overwrites xb
    int* flag = big ? (int*)(xb + HSZ) : (int*)(R + HSZ);

    detect_k<<<1, 256, 0, stream>>>((const unsigned short*)wqkv, flag);
    transpose_w_k<<<dim3(3 * Cn / 64, Cn / 64), 256, 0, stream>>>(wqkv, wqkvT, Cn, 3 * Cn, flag);
    if (big) {
        convert_x_k<<<(Mn * Cn) / (256 * 8), 256, 0, stream>>>(x, xb, flag);
        gemm_lds<1><<<dim3(3 * Cn / 128, Mn / 128), 256, 0, stream>>>(
            xb, wqkvT, nullptr, q, k, v, Mn, 3 * Cn, Cn, flag);
        transpose_v_k<<<dim3(Tn / 64, Bn * Hn), 256, 0, stream>>>(v, vt);
        attn_mfma2<<<dim3(Tn / 128, Bn * Hn), 256, 0, stream>>>(q, k, vt, y);
    } else {
        gemm_qkv_fb<<<dim3(3 * Cn / 128, Mn / 128), 256, 0, stream>>>(
            x, wqkvT, q, k, v, Mn, 3 * Cn, Cn, flag);
        attn_mfma_fb<<<dim3(Tn / 128, Bn * Hn), 256, 0, stream>>>(q, k, v, y);
    }
    transpose_w_k<<<dim3(Cn / 64, Cn / 64), 256, 0, stream>>>(wproj, wprojT, Cn, Cn, flag);
    gemm_lds<0><<<dim3(Cn / 128, Mn / 128), 256, 0, stream>>>(
        y, wprojT, d_out, nullptr, nullptr, nullptr, Mn, Cn, Cn, flag);
}

// Round 3
// 361.799 us; speedup vs baseline: 1.0397x; 1.0397x over previous
//
#include <hip/hip_runtime.h>
#include <hip/hip_bf16.h>

#define Bn 2
#define Tn 4096
#define Cn 768
#define Hn 12
#define Dn 64
#define Mn (Bn * Tn)   // 8192
#define PAD 72         // padded LDS row stride (bf16 elems) for attn/transpose

typedef __attribute__((ext_vector_type(8))) short bf16x8;
typedef __attribute__((ext_vector_type(4))) float f32x4;

typedef const __attribute__((address_space(1))) unsigned int* gas_ptr;
typedef __attribute__((address_space(3))) unsigned int* las_ptr;

__device__ __forceinline__ float b2f(unsigned short u) {
    return __uint_as_float(((unsigned int)u) << 16);
}
__device__ __forceinline__ unsigned short f2b(float f) {
    unsigned int x = __float_as_uint(f);
    x += 0x7FFFu + ((x >> 16) & 1u);   // round-to-nearest-even
    return (unsigned short)(x >> 16);
}
// packed f32x2 -> bf16x2 (single VALU op; replaces 2x f2b = ~6 ops)
__device__ __forceinline__ unsigned int cvt_pk_bf16(float lo, float hi) {
    unsigned int r;
    asm("v_cvt_pk_bf16_f32 %0, %1, %2" : "=v"(r) : "v"(lo), "v"(hi));
    return r;
}

// Async global->LDS, 16B/lane. LDS dest = wave-uniform base + lane*16.
__device__ __forceinline__ void async_ld16(const unsigned short* g, unsigned short* l) {
    __builtin_amdgcn_global_load_lds((gas_ptr)(const void*)g, (las_ptr)(void*)l, 16, 0, 0);
}

// ---------------------------------------------------------------------------
// Input dtype detection (fp32 read as bf16 halves shows huge exponents).
// ---------------------------------------------------------------------------
__global__ void detect_k(const unsigned short* __restrict__ W, int* __restrict__ flag) {
    __shared__ int any;
    if (threadIdx.x == 0) any = 0;
    __syncthreads();
    int bad = 0;
    for (int i = threadIdx.x; i < 65536; i += 256) {
        const unsigned int e = (W[i] >> 7) & 0xFFu;
        bad |= (e >= 0x88u) ? 1 : 0;
    }
    if (bad) atomicOr(&any, 1);
    __syncthreads();
    if (threadIdx.x == 0) *flag = any;
}

// Convert x (fp32 or bf16 per flag) -> bf16 flat copy. 8 elems/thread.
__global__ __launch_bounds__(256) void convert_x_k(
    const void* __restrict__ in, unsigned short* __restrict__ out,
    const int* __restrict__ flag)
{
    const size_t i = ((size_t)blockIdx.x * 256 + threadIdx.x) * 8;
    union { int4 v; unsigned short u[8]; } pk;
    if (*flag) {
        const float* p = (const float*)in + i;
        float4 a = *reinterpret_cast<const float4*>(p);
        float4 b = *reinterpret_cast<const float4*>(p + 4);
        float t[8] = {a.x, a.y, a.z, a.w, b.x, b.y, b.z, b.w};
#pragma unroll
        for (int j = 0; j < 8; ++j) pk.u[j] = f2b(t[j]);
    } else {
        pk.v = *reinterpret_cast<const int4*>((const unsigned short*)in + i);
    }
    *reinterpret_cast<int4*>(out + i) = pk.v;
}

// Transpose weight: in[K][N] (fp32 or bf16 per flag) -> out[N][K] bf16. 64x64 tiles.
__global__ __launch_bounds__(256) void transpose_w_k(
    const void* __restrict__ in, unsigned short* __restrict__ out,
    int K, int N, const int* __restrict__ flag)
{
    __shared__ unsigned short Ts[64][PAD];   // [n][k]
    const int tid = threadIdx.x;
    const int kB = blockIdx.y * 64, nB = blockIdx.x * 64;
    const bool f32 = (*flag != 0);
#pragma unroll
    for (int it = 0; it < 2; ++it) {
        const int r = (tid >> 3) + it * 32;   // k-row in tile
        const int c = (tid & 7) * 8;          // n-col chunk
        float t[8];
        if (f32) {
            const float* p = (const float*)in + (size_t)(kB + r) * N + nB + c;
            float4 a = *reinterpret_cast<const float4*>(p);
            float4 b = *reinterpret_cast<const float4*>(p + 4);
            t[0]=a.x;t[1]=a.y;t[2]=a.z;t[3]=a.w;t[4]=b.x;t[5]=b.y;t[6]=b.z;t[7]=b.w;
        } else {
            int4 v = *reinterpret_cast<const int4*>((const unsigned short*)in + (size_t)(kB + r) * N + nB + c);
            const unsigned short* u = reinterpret_cast<const unsigned short*>(&v);
#pragma unroll
            for (int j = 0; j < 8; ++j) t[j] = b2f(u[j]);
        }
#pragma unroll
        for (int j = 0; j < 8; ++j) Ts[c + j][r] = f2b(t[j]);
    }
    __syncthreads();
#pragma unroll
    for (int it = 0; it < 2; ++it) {
        const int n = (tid >> 3) + it * 32;
        const int k = (tid & 7) * 8;
        *reinterpret_cast<int4*>(out + (size_t)(nB + n) * K + kB + k) =
            *reinterpret_cast<const int4*>(&Ts[n][k]);
    }
}

// Transpose V per head: [T][D] -> [D][T], bf16. 64x64 tiles.
__global__ __launch_bounds__(256) void transpose_v_k(
    const unsigned short* __restrict__ Vin, unsigned short* __restrict__ Vt)
{
    __shared__ unsigned short Ts[64][PAD];
    const int tid = threadIdx.x;
    const size_t base = (size_t)blockIdx.y * Tn * Dn;
    const int t0 = blockIdx.x * 64;
#pragma unroll
    for (int it = 0; it < 2; ++it) {
        const int r = (tid >> 3) + it * 32;     // t-row
        const int c = (tid & 7) * 8;            // d chunk
        int4 vv = *reinterpret_cast<const int4*>(Vin + base + (size_t)(t0 + r) * Dn + c);
        const unsigned short* u = reinterpret_cast<const unsigned short*>(&vv);
#pragma unroll
        for (int j = 0; j < 8; ++j) Ts[c + j][r] = u[j];
    }
    __syncthreads();
#pragma unroll
    for (int it = 0; it < 2; ++it) {
        const int d = (tid >> 3) + it * 32;
        const int tc = (tid & 7) * 8;
        *reinterpret_cast<int4*>(Vt + base + (size_t)d * Tn + t0 + tc) =
            *reinterpret_cast<const int4*>(&Ts[d][tc]);
    }
}

// ---------------------------------------------------------------------------
// m97-style MFMA GEMM: C[M,N] = A[M,K]*Bt[N,K]^T, A/Bt bf16, fp32 accum.
// 128x128 tile, BK=64, 4 waves (64x64 quadrant each). Fragment-order LDS
// staging via global_load_lds. EPI==0: row-major store. EPI==1: QKV split.
// ---------------------------------------------------------------------------
template <int EPI>
__global__ __launch_bounds__(256) void gemm_lds(
    const unsigned short* __restrict__ A, const unsigned short* __restrict__ Bt,
    void* __restrict__ Out, unsigned short* __restrict__ Qo,
    unsigned short* __restrict__ Ko, unsigned short* __restrict__ Vo,
    int M, int N, int K, const int* __restrict__ flag)
{
    __shared__ unsigned short As[8192];   // 16 chunks x 512 elems
    __shared__ unsigned short Bs[8192];
    const int tid = threadIdx.x;
    const int w = tid >> 6, l = tid & 63;
    const int l15 = l & 15, l4 = l >> 4;
    const int rowBase = blockIdx.y * 128;
    const int colBase = blockIdx.x * 128;
    const int mq = (w & 1) * 64, nq = (w >> 1) * 64;
    const bool f32 = (*flag != 0);

    const int laneRow = l15, laneK = l4 * 8;

    f32x4 acc[4][4];
#pragma unroll
    for (int i = 0; i < 4; ++i)
#pragma unroll
        for (int j = 0; j < 4; ++j) acc[i][j] = (f32x4){0.f, 0.f, 0.f, 0.f};

    for (int k0 = 0; k0 < K; k0 += 64) {
        __syncthreads();
#pragma unroll
        for (int j = 0; j < 4; ++j) {
            const int c = w * 4 + j;
            const int mt_g = c >> 1, kh = c & 1;
            const size_t ga = (size_t)(rowBase + mt_g * 16 + laneRow) * K + k0 + kh * 32 + laneK;
            const size_t gb = (size_t)(colBase + mt_g * 16 + laneRow) * K + k0 + kh * 32 + laneK;
            async_ld16(A + ga, &As[c * 512]);
            async_ld16(Bt + gb, &Bs[c * 512]);
        }
        __syncthreads();

#pragma unroll
        for (int kh = 0; kh < 2; ++kh) {
            bf16x8 af[4], bf[4];
#pragma unroll
            for (int mt = 0; mt < 4; ++mt)
                af[mt] = *reinterpret_cast<const bf16x8*>(
                    &As[(((mq >> 4) + mt) * 2 + kh) * 512 + l * 8]);
#pragma unroll
            for (int nt = 0; nt < 4; ++nt)
                bf[nt] = *reinterpret_cast<const bf16x8*>(
                    &Bs[(((nq >> 4) + nt) * 2 + kh) * 512 + l * 8]);
#pragma unroll
            for (int mt = 0; mt < 4; ++mt)
#pragma unroll
                for (int nt = 0; nt < 4; ++nt)
                    acc[mt][nt] = __builtin_amdgcn_mfma_f32_16x16x32_bf16(af[mt], bf[nt], acc[mt][nt], 0, 0, 0);
        }
    }

#pragma unroll
    for (int mt = 0; mt < 4; ++mt)
#pragma unroll
        for (int i = 0; i < 4; ++i) {
            const int m = rowBase + mq + mt * 16 + l4 * 4 + i;
#pragma unroll
            for (int nt = 0; nt < 4; ++nt) {
                const int n0 = colBase + nq + nt * 16 + l15;
                if (EPI == 0) {
                    if (f32) ((float*)Out)[(size_t)m * N + n0] = acc[mt][nt][i];
                    else ((unsigned short*)Out)[(size_t)m * N + n0] = f2b(acc[mt][nt][i]);
                } else {
                    const int sec = n0 / 768;
                    const int cc = n0 - sec * 768;
                    const int h = cc >> 6, d = cc & 63;
                    const int b = m >> 12, t = m & 4095;
                    unsigned short* dst = (sec == 0) ? Qo : (sec == 1) ? Ko : Vo;
                    dst[(((size_t)(b * Hn + h) * Tn + t) * Dn) + d] = f2b(acc[mt][nt][i]);
                }
            }
        }
}

// ---------------------------------------------------------------------------
// Fallback QKV GEMM (verified): VGPR staging with inline fp32->bf16.
// ---------------------------------------------------------------------------
__global__ __launch_bounds__(256) void gemm_qkv_fb(
    const void* __restrict__ A, const unsigned short* __restrict__ Bt,
    unsigned short* __restrict__ Qo, unsigned short* __restrict__ Ko,
    unsigned short* __restrict__ Vo, int M, int N, int K,
    const int* __restrict__ flag)
{
    __shared__ unsigned short As[128 * PAD];
    __shared__ unsigned short Bs[128 * PAD];
    const int tid = threadIdx.x;
    const int w = tid >> 6, l = tid & 63;
    const int l15 = l & 15, l4 = l >> 4;
    const int rowBase = blockIdx.y * 128;
    const int colBase = blockIdx.x * 128;
    const int mq = (w & 1) * 64, nq = (w >> 1) * 64;
    const bool af32 = (*flag != 0);

    f32x4 acc[4][4];
#pragma unroll
    for (int i = 0; i < 4; ++i)
#pragma unroll
        for (int j = 0; j < 4; ++j) acc[i][j] = (f32x4){0.f, 0.f, 0.f, 0.f};

    for (int k0 = 0; k0 < K; k0 += 64) {
        __syncthreads();
#pragma unroll
        for (int it = 0; it < 4; ++it) {
            const int s = tid + it * 256;
            const int r = s >> 3, c = (s & 7) * 8;
            union { int4 v; unsigned short u[8]; } pk;
            if (af32) {
                const float* p = (const float*)A + (size_t)(rowBase + r) * K + k0 + c;
                float4 a = *reinterpret_cast<const float4*>(p);
                float4 b = *reinterpret_cast<const float4*>(p + 4);
                float t[8] = {a.x, a.y, a.z, a.w, b.x, b.y, b.z, b.w};
#pragma unroll
                for (int j = 0; j < 8; ++j) pk.u[j] = f2b(t[j]);
            } else {
                pk.v = *reinterpret_cast<const int4*>(
                    (const unsigned short*)A + (size_t)(rowBase + r) * K + k0 + c);
            }
            *reinterpret_cast<int4*>(&As[r * PAD + c]) = pk.v;
            *reinterpret_cast<int4*>(&Bs[r * PAD + c]) =
                *reinterpret_cast<const int4*>(Bt + (size_t)(colBase + r) * K + k0 + c);
        }
        __syncthreads();
#pragma unroll
        for (int kk = 0; kk < 64; kk += 32) {
            bf16x8 af[4], bf[4];
#pragma unroll
            for (int mt = 0; mt < 4; ++mt)
                af[mt] = *reinterpret_cast<const bf16x8*>(&As[(mq + mt * 16 + l15) * PAD + kk + l4 * 8]);
#pragma unroll
            for (int nt = 0; nt < 4; ++nt)
                bf[nt] = *reinterpret_cast<const bf16x8*>(&Bs[(nq + nt * 16 + l15) * PAD + kk + l4 * 8]);
#pragma unroll
            for (int mt = 0; mt < 4; ++mt)
#pragma unroll
                for (int nt = 0; nt < 4; ++nt)
                    acc[mt][nt] = __builtin_amdgcn_mfma_f32_16x16x32_bf16(af[mt], bf[nt], acc[mt][nt], 0, 0, 0);
        }
    }

#pragma unroll
    for (int mt = 0; mt < 4; ++mt)
#pragma unroll
        for (int i = 0; i < 4; ++i) {
            const int m = rowBase + mq + mt * 16 + l4 * 4 + i;
#pragma unroll
            for (int nt = 0; nt < 4; ++nt) {
                const int n0 = colBase + nq + nt * 16 + l15;
                const int sec = n0 / 768;
                const int cc = n0 - sec * 768;
                const int h = cc >> 6, d = cc & 63;
                const int b = m >> 12, t = m & 4095;
                unsigned short* dst = (sec == 0) ? Qo : (sec == 1) ? Ko : Vo;
                dst[(((size_t)(b * Hn + h) * Tn + t) * Dn) + d] = f2b(acc[mt][nt][i]);
            }
        }
}

// ---------------------------------------------------------------------------
// MFMA flash attention v3: v2 + XCD-aware bh grouping + double-buffered DMA.
//
// - XCD grouping: flat id f = y*32+x; XCD (f%8) owns bh {3r,3r+1,3r+2}
//   (3 MB K+V^T working set < 4 MB XCD-L2; was sprayed over all 24 bh ->
//   200 MB HBM fetch, L2-miss latency exposed every stage).
// - Double buffer: per stage, ONE barrier; issue next tile's global_load_lds
//   into buf^1 right after it, then compute buf. The next barrier's implicit
//   vmcnt(0) waits for loads that had the whole compute phase to land ->
//   DMA latency hidden, one barrier saved per stage.
// - Compute/fragment layout identical to verified v2 (swapped QK^T, in-lane
//   P packing via v_cvt_pk_bf16_f32, wave-private Ps strip).
// ---------------------------------------------------------------------------
__global__ __launch_bounds__(256, 4) void attn_mfma2(
    const unsigned short* __restrict__ Q, const unsigned short* __restrict__ K,
    const unsigned short* __restrict__ Vt, unsigned short* __restrict__ Y)
{
    __shared__ unsigned short Ks[2][8 * 512];   // chunk (tt,kh): 16 keys x 32 d
    __shared__ unsigned short Vs[2][8 * 512];   // chunk (dt,kh): 16 d x 32 keys
    __shared__ unsigned short Ps[64 * PAD];     // [q-local][key]

    const int tid = threadIdx.x;
    const int w = tid >> 6, l = tid & 63;    // 4 waves x 16 q-rows
    const int l15 = l & 15, l4 = l >> 4;

    // XCD-aware remap: XCD r = f%8 handles bh in [3r, 3r+3)
    const int f = (int)blockIdx.y * 32 + (int)blockIdx.x;
    const int r8 = f & 7, j = f >> 3;
    const int bh = r8 * 3 + (j >> 5);
    const int xq = j & 31;

    const size_t base = (size_t)bh * Tn * Dn;   // same size for K ([T][D]) and Vt ([D][T])
    const float sc = 0.125f * 1.44269504088896f;   // D^-0.5 * log2(e)
    const int b = bh / Hn, h = bh - b * Hn;

    for (int half = 0; half < 2; ++half) {
        const int t = half ? xq : (63 - xq);
        const int q0 = t * 64;
        const int qrow = q0 + w * 16 + l15;    // this lane's q (swapped layout)

        bf16x8 aq[2];
#pragma unroll
        for (int kh = 0; kh < 2; ++kh)
            aq[kh] = *reinterpret_cast<const bf16x8*>(
                Q + base + (size_t)qrow * Dn + kh * 32 + l4 * 8);

        f32x4 o[4];
#pragma unroll
        for (int dt = 0; dt < 4; ++dt) o[dt] = (f32x4){0.f, 0.f, 0.f, 0.f};
        float lsum = 0.f;

        const int nst = (q0 >> 6) + 1;   // 64-key stages this half

        // prologue: all waves done reading LDS (prev half) before overwrite
        __syncthreads();
#pragma unroll
        for (int jj = 0; jj < 2; ++jj) {     // stage tile 0 -> buf 0
            const int c = w * 2 + jj;
            const int sub = c >> 1, kh = c & 1;
            async_ld16(K + base + (size_t)(sub * 16 + l15) * Dn + kh * 32 + l4 * 8,
                       &Ks[0][c * 512]);
            async_ld16(Vt + base + (size_t)(sub * 16 + l15) * Tn + kh * 32 + l4 * 8,
                       &Vs[0][c * 512]);
        }

        int cur = 0;
        for (int s = 0; s < nst; ++s) {
            const int k0 = s << 6;
            __syncthreads();   // implicit vmcnt(0): buf[cur] complete; joins waves

            if (s + 1 < nst) {   // prefetch next tile into buf[cur^1]
                const int kn = k0 + 64;
#pragma unroll
                for (int jj = 0; jj < 2; ++jj) {
                    const int c = w * 2 + jj;
                    const int sub = c >> 1, kh = c & 1;
                    async_ld16(K + base + (size_t)(kn + sub * 16 + l15) * Dn + kh * 32 + l4 * 8,
                               &Ks[cur ^ 1][c * 512]);
                    async_ld16(Vt + base + (size_t)(sub * 16 + l15) * Tn + kn + kh * 32 + l4 * 8,
                               &Vs[cur ^ 1][c * 512]);
                }
            }

            // S^T = K Q^T: C[col=q(l15)][row=key(l4*4+i)] per key-subtile tt
            f32x4 sfr[4];
#pragma unroll
            for (int tt = 0; tt < 4; ++tt) {
                bf16x8 ak0 = *reinterpret_cast<const bf16x8*>(&Ks[cur][(tt * 2 + 0) * 512 + l * 8]);
                bf16x8 ak1 = *reinterpret_cast<const bf16x8*>(&Ks[cur][(tt * 2 + 1) * 512 + l * 8]);
                f32x4 z = (f32x4){0.f, 0.f, 0.f, 0.f};
                z = __builtin_amdgcn_mfma_f32_16x16x32_bf16(ak0, aq[0], z, 0, 0, 0);
                z = __builtin_amdgcn_mfma_f32_16x16x32_bf16(ak1, aq[1], z, 0, 0, 0);
                sfr[tt] = z;
            }

            // p = exp2(s*sc), causal mask only on the last stage
            const bool need_mask = (k0 + 63 > q0);
            float p[4][4];
#pragma unroll
            for (int tt = 0; tt < 4; ++tt)
#pragma unroll
                for (int i = 0; i < 4; ++i) {
                    float s2 = sfr[tt][i] * sc;
                    if (need_mask && (k0 + tt * 16 + l4 * 4 + i > qrow)) s2 = -1e30f;
                    const float e = exp2f(s2);
                    p[tt][i] = e;
                    lsum += e;
                }

            // pack P (keys contiguous in-lane) and write wave-private strip
#pragma unroll
            for (int tt = 0; tt < 4; ++tt) {
                uint2 pw;
                pw.x = cvt_pk_bf16(p[tt][0], p[tt][1]);
                pw.y = cvt_pk_bf16(p[tt][2], p[tt][3]);
                *reinterpret_cast<uint2*>(&Ps[(w * 16 + l15) * PAD + tt * 16 + l4 * 4]) = pw;
            }

            bf16x8 ap0 = *reinterpret_cast<const bf16x8*>(&Ps[(w * 16 + l15) * PAD + l4 * 8]);
            bf16x8 ap1 = *reinterpret_cast<const bf16x8*>(&Ps[(w * 16 + l15) * PAD + 32 + l4 * 8]);
#pragma unroll
            for (int dt = 0; dt < 4; ++dt) {
                bf16x8 bv0 = *reinterpret_cast<const bf16x8*>(&Vs[cur][(dt * 2 + 0) * 512 + l * 8]);
                bf16x8 bv1 = *reinterpret_cast<const bf16x8*>(&Vs[cur][(dt * 2 + 1) * 512 + l * 8]);
                o[dt] = __builtin_amdgcn_mfma_f32_16x16x32_bf16(ap0, bv0, o[dt], 0, 0, 0);
                o[dt] = __builtin_amdgcn_mfma_f32_16x16x32_bf16(ap1, bv1, o[dt], 0, 0, 0);
            }
            cur ^= 1;
        }

        // reduce lsum across the 4 l4-groups sharing q=l15
        lsum += __shfl_xor(lsum, 16);
        lsum += __shfl_xor(lsum, 32);

#pragma unroll
        for (int i = 0; i < 4; ++i) {
            // output row q-local = l4*4+i; its lsum lives at lane l15 == l4*4+i
            const float lv = __shfl(lsum, (l & 48) + (l4 * 4 + i));
            const float inv = 1.0f / lv;
            const int row = q0 + w * 16 + l4 * 4 + i;
#pragma unroll
            for (int dt = 0; dt < 4; ++dt)
                Y[((size_t)(b * Tn + row)) * Cn + h * 64 + dt * 16 + l15] = f2b(o[dt][i] * inv);
        }
    }
}

// ---------------------------------------------------------------------------
// Fallback attention (round-1 verified, no V^T buffer needed).
// ---------------------------------------------------------------------------
__global__ __launch_bounds__(256, 3) void attn_mfma_fb(
    const unsigned short* __restrict__ Q, const unsigned short* __restrict__ K,
    const unsigned short* __restrict__ V, unsigned short* __restrict__ Y)
{
    __shared__ unsigned short Ks[96 * PAD];
    __shared__ unsigned short Vtl[96 * PAD];
    __shared__ unsigned short Ps[96 * PAD];

    const int tid = threadIdx.x;
    const int w = tid >> 6, l = tid & 63;
    const int l15 = l & 15, l4 = l >> 4;
    const int bh = blockIdx.y;
    const size_t base = (size_t)bh * Tn * Dn;
    const float sc = 0.125f * 1.44269504088896f;
    const int b = bh / Hn, h = bh - b * Hn;

    for (int half = 0; half < 2; ++half) {
        const int t = half ? (int)blockIdx.x : (63 - (int)blockIdx.x);
        const int q0 = t * 64;

        bf16x8 aq[2];
#pragma unroll
        for (int kh = 0; kh < 2; ++kh)
            aq[kh] = *reinterpret_cast<const bf16x8*>(
                Q + base + (size_t)(q0 + w * 16 + l15) * Dn + kh * 32 + l4 * 8);

        f32x4 o[4];
#pragma unroll
        for (int dt = 0; dt < 4; ++dt) o[dt] = (f32x4){0.f, 0.f, 0.f, 0.f};
        float l_i[4] = {0.f, 0.f, 0.f, 0.f};

        const int kend = q0 + 64;
        for (int k0 = 0; k0 < kend; k0 += 64) {
            __syncthreads();
#pragma unroll
            for (int it = 0; it < 2; ++it) {
                const int s = tid + it * 256;
                const int r = s >> 3, c = (s & 7) * 8;
                *reinterpret_cast<int4*>(&Ks[r * PAD + c]) =
                    *reinterpret_cast<const int4*>(K + base + (size_t)(k0 + r) * Dn + c);
            }
#pragma unroll
            for (int it = 0; it < 2; ++it) {
                const int r = tid & 63, d0 = (tid >> 6) * 8 + it * 32;
                int4 vv = *reinterpret_cast<const int4*>(V + base + (size_t)(k0 + r) * Dn + d0);
                const unsigned short* vu = reinterpret_cast<const unsigned short*>(&vv);
#pragma unroll
                for (int j = 0; j < 8; ++j) Vtl[(d0 + j) * PAD + r] = vu[j];
            }
            __syncthreads();

            f32x4 sfr[4];
#pragma unroll
            for (int tt = 0; tt < 4; ++tt) {
                bf16x8 bk0 = *reinterpret_cast<const bf16x8*>(&Ks[(tt * 16 + l15) * PAD + l4 * 8]);
                bf16x8 bk1 = *reinterpret_cast<const bf16x8*>(&Ks[(tt * 16 + l15) * PAD + 32 + l4 * 8]);
                f32x4 z = (f32x4){0.f, 0.f, 0.f, 0.f};
                z = __builtin_amdgcn_mfma_f32_16x16x32_bf16(aq[0], bk0, z, 0, 0, 0);
                z = __builtin_amdgcn_mfma_f32_16x16x32_bf16(aq[1], bk1, z, 0, 0, 0);
                sfr[tt] = z;
            }

            const bool need_mask = (k0 + 63 > q0);
            float p[4][4];
#pragma unroll
            for (int tt = 0; tt < 4; ++tt) {
                const int cb = k0 + tt * 16 + l15;
                const int rb = q0 + w * 16 + l4 * 4;
#pragma unroll
                for (int i = 0; i < 4; ++i) {
                    float s = sfr[tt][i] * sc;
                    if (need_mask && (cb > rb + i)) s = -1e30f;
                    const float e = exp2f(s);
                    p[tt][i] = e;
                    l_i[i] += e;
                }
            }

#pragma unroll
            for (int tt = 0; tt < 4; ++tt)
#pragma unroll
                for (int i = 0; i < 4; ++i)
                    Ps[(w * 16 + l4 * 4 + i) * PAD + tt * 16 + l15] = f2b(p[tt][i]);

            bf16x8 ap0 = *reinterpret_cast<const bf16x8*>(&Ps[(w * 16 + l15) * PAD + l4 * 8]);
            bf16x8 ap1 = *reinterpret_cast<const bf16x8*>(&Ps[(w * 16 + l15) * PAD + 32 + l4 * 8]);
#pragma unroll
            for (int dt = 0; dt < 4; ++dt) {
                bf16x8 bv0 = *reinterpret_cast<const bf16x8*>(&Vtl[(dt * 16 + l15) * PAD + l4 * 8]);
                bf16x8 bv1 = *reinterpret_cast<const bf16x8*>(&Vtl[(dt * 16 + l15) * PAD + 32 + l4 * 8]);
                o[dt] = __builtin_amdgcn_mfma_f32_16x16x32_bf16(ap0, bv0, o[dt], 0, 0, 0);
                o[dt] = __builtin_amdgcn_mfma_f32_16x16x32_bf16(ap1, bv1, o[dt], 0, 0, 0);
            }
        }

#pragma unroll
        for (int i = 0; i < 4; ++i)
#pragma unroll
            for (int off = 1; off < 16; off <<= 1) l_i[i] += __shfl_xor(l_i[i], off);

#pragma unroll
        for (int i = 0; i < 4; ++i) {
            const float inv = 1.0f / l_i[i];
            const int row = q0 + w * 16 + l4 * 4 + i;
#pragma unroll
            for (int dt = 0; dt < 4; ++dt)
                Y[((size_t)(b * Tn + row)) * Cn + h * 64 + dt * 16 + l15] = f2b(o[dt][i] * inv);
        }
    }
}

extern "C" void kernel_launch(void* const* d_in, const int* in_sizes, int n_in,
                              void* d_out, int out_size, void* d_ws, size_t ws_size,
                              hipStream_t stream)
{
    const void* x = d_in[0];
    const void* wqkv = d_in[1];
    const void* wproj = d_in[2];
    const size_t HSZ = (size_t)Bn * Hn * Tn * Dn;   // 6291456 elems
    unsigned short* q = (unsigned short*)d_ws;
    unsigned short* k = q + HSZ;
    unsigned short* v = k + HSZ;
    unsigned short* R = v + HSZ;          // wqkvT during QKV gemm, y afterwards
    unsigned short* wqkvT = R;            // [2304][768] = 1769472 elems <= HSZ
    unsigned short* y = R;
    unsigned short* wprojT = q;           // [768][768], reused after attn
    // Big layout adds xb (bf16 copy of x) at 4*HSZ; vt reuses xb after the
    // QKV gemm (both HSZ elems). Need 5*HSZ*2+16 bytes.
    const bool big = ws_size >= (size_t)5 * HSZ * 2 + 16;
    unsigned short* xb = R + HSZ;
    unsigned short* vt = xb;              // V^T [B,H,D,T], overwrites xb
    int* flag = big ? (int*)(xb + HSZ) : (int*)(R + HSZ);

    detect_k<<<1, 256, 0, stream>>>((const unsigned short*)wqkv, flag);
    transpose_w_k<<<dim3(3 * Cn / 64, Cn / 64), 256, 0, stream>>>(wqkv, wqkvT, Cn, 3 * Cn, flag);
    if (big) {
        convert_x_k<<<(Mn * Cn) / (256 * 8), 256, 0, stream>>>(x, xb, flag);
        gemm_lds<1><<<dim3(3 * Cn / 128, Mn / 128), 256, 0, stream>>>(
            xb, wqkvT, nullptr, q, k, v, Mn, 3 * Cn, Cn, flag);
        transpose_v_k<<<dim3(Tn / 64, Bn * Hn), 256, 0, stream>>>(v, vt);
        attn_mfma2<<<dim3(Tn / 128, Bn * Hn), 256, 0, stream>>>(q, k, vt, y);
    } else {
        gemm_qkv_fb<<<dim3(3 * Cn / 128, Mn / 128), 256, 0, stream>>>(
            x, wqkvT, q, k, v, Mn, 3 * Cn, Cn, flag);
        attn_mfma_fb<<<dim3(Tn / 128, Bn * Hn), 256, 0, stream>>>(q, k, v, y);
    }
    transpose_w_k<<<dim3(Cn / 64, Cn / 64), 256, 0, stream>>>(wproj, wprojT, Cn, Cn, flag);
    gemm_lds<0><<<dim3(Cn / 128, Mn / 128), 256, 0, stream>>>(
        y, wprojT, d_out, nullptr, nullptr, nullptr, Mn, Cn, Cn, flag);
}

// Round 4
// 327.340 us; speedup vs baseline: 1.1492x; 1.1053x over previous
//
#include <hip/hip_runtime.h>
#include <hip/hip_bf16.h>

#define Bn 2
#define Tn 4096
#define Cn 768
#define Hn 12
#define Dn 64
#define Mn (Bn * Tn)   // 8192
#define PAD 72         // padded LDS row stride (bf16 elems) for attn/transpose

typedef __attribute__((ext_vector_type(8))) short bf16x8;
typedef __attribute__((ext_vector_type(4))) short bf16x4;
typedef __attribute__((ext_vector_type(4))) float f32x4;

typedef const __attribute__((address_space(1))) unsigned int* gas_ptr;
typedef __attribute__((address_space(3))) unsigned int* las_ptr;

__device__ __forceinline__ float b2f(unsigned short u) {
    return __uint_as_float(((unsigned int)u) << 16);
}
__device__ __forceinline__ unsigned short f2b(float f) {
    unsigned int x = __float_as_uint(f);
    x += 0x7FFFu + ((x >> 16) & 1u);   // round-to-nearest-even
    return (unsigned short)(x >> 16);
}
// packed f32x2 -> bf16x2 (single VALU op)
__device__ __forceinline__ unsigned int cvt_pk_bf16(float lo, float hi) {
    unsigned int r;
    asm("v_cvt_pk_bf16_f32 %0, %1, %2" : "=v"(r) : "v"(lo), "v"(hi));
    return r;
}

// Async global->LDS, 16B/lane. LDS dest = wave-uniform base + lane*16.
__device__ __forceinline__ void async_ld16(const unsigned short* g, unsigned short* l) {
    __builtin_amdgcn_global_load_lds((gas_ptr)(const void*)g, (las_ptr)(void*)l, 16, 0, 0);
}

// ---------------------------------------------------------------------------
// Input dtype detection (fp32 read as bf16 halves shows huge exponents).
// One int4 per thread (2048 samples): fp32 low-halves have uniform-random
// exponents -> >= 0x88 with p~0.47; bf16 N(0,.036) never reaches 0x88.
// Single iteration, fully pipelined (old version: 256 serial strided loads).
// ---------------------------------------------------------------------------
__global__ void detect_k(const unsigned short* __restrict__ W, int* __restrict__ flag) {
    __shared__ int any;
    if (threadIdx.x == 0) any = 0;
    __syncthreads();
    int4 v = reinterpret_cast<const int4*>(W)[threadIdx.x];
    const unsigned short* u = reinterpret_cast<const unsigned short*>(&v);
    int bad = 0;
#pragma unroll
    for (int j = 0; j < 8; ++j) {
        const unsigned int e = (u[j] >> 7) & 0xFFu;
        bad |= (e >= 0x88u) ? 1 : 0;
    }
    if (bad) atomicOr(&any, 1);
    __syncthreads();
    if (threadIdx.x == 0) *flag = any;
}

// Convert x (fp32 or bf16 per flag) -> bf16 flat copy. 8 elems/thread.
__global__ __launch_bounds__(256) void convert_x_k(
    const void* __restrict__ in, unsigned short* __restrict__ out,
    const int* __restrict__ flag)
{
    const size_t i = ((size_t)blockIdx.x * 256 + threadIdx.x) * 8;
    union { int4 v; unsigned short u[8]; } pk;
    if (*flag) {
        const float* p = (const float*)in + i;
        float4 a = *reinterpret_cast<const float4*>(p);
        float4 b = *reinterpret_cast<const float4*>(p + 4);
        float t[8] = {a.x, a.y, a.z, a.w, b.x, b.y, b.z, b.w};
#pragma unroll
        for (int j = 0; j < 8; ++j) pk.u[j] = f2b(t[j]);
    } else {
        pk.v = *reinterpret_cast<const int4*>((const unsigned short*)in + i);
    }
    *reinterpret_cast<int4*>(out + i) = pk.v;
}

// Transpose weight: in[K][N] (fp32 or bf16 per flag) -> out[N][K] bf16. 64x64 tiles.
__global__ __launch_bounds__(256) void transpose_w_k(
    const void* __restrict__ in, unsigned short* __restrict__ out,
    int K, int N, const int* __restrict__ flag)
{
    __shared__ unsigned short Ts[64][PAD];   // [n][k]
    const int tid = threadIdx.x;
    const int kB = blockIdx.y * 64, nB = blockIdx.x * 64;
    const bool f32 = (*flag != 0);
#pragma unroll
    for (int it = 0; it < 2; ++it) {
        const int r = (tid >> 3) + it * 32;   // k-row in tile
        const int c = (tid & 7) * 8;          // n-col chunk
        float t[8];
        if (f32) {
            const float* p = (const float*)in + (size_t)(kB + r) * N + nB + c;
            float4 a = *reinterpret_cast<const float4*>(p);
            float4 b = *reinterpret_cast<const float4*>(p + 4);
            t[0]=a.x;t[1]=a.y;t[2]=a.z;t[3]=a.w;t[4]=b.x;t[5]=b.y;t[6]=b.z;t[7]=b.w;
        } else {
            int4 v = *reinterpret_cast<const int4*>((const unsigned short*)in + (size_t)(kB + r) * N + nB + c);
            const unsigned short* u = reinterpret_cast<const unsigned short*>(&v);
#pragma unroll
            for (int j = 0; j < 8; ++j) t[j] = b2f(u[j]);
        }
#pragma unroll
        for (int j = 0; j < 8; ++j) Ts[c + j][r] = f2b(t[j]);
    }
    __syncthreads();
#pragma unroll
    for (int it = 0; it < 2; ++it) {
        const int n = (tid >> 3) + it * 32;
        const int k = (tid & 7) * 8;
        *reinterpret_cast<int4*>(out + (size_t)(nB + n) * K + kB + k) =
            *reinterpret_cast<const int4*>(&Ts[n][k]);
    }
}

// Transpose V per head: [T][D] -> [D][T], bf16. 64x64 tiles.
__global__ __launch_bounds__(256) void transpose_v_k(
    const unsigned short* __restrict__ Vin, unsigned short* __restrict__ Vt)
{
    __shared__ unsigned short Ts[64][PAD];
    const int tid = threadIdx.x;
    const size_t base = (size_t)blockIdx.y * Tn * Dn;
    const int t0 = blockIdx.x * 64;
#pragma unroll
    for (int it = 0; it < 2; ++it) {
        const int r = (tid >> 3) + it * 32;     // t-row
        const int c = (tid & 7) * 8;            // d chunk
        int4 vv = *reinterpret_cast<const int4*>(Vin + base + (size_t)(t0 + r) * Dn + c);
        const unsigned short* u = reinterpret_cast<const unsigned short*>(&vv);
#pragma unroll
        for (int j = 0; j < 8; ++j) Ts[c + j][r] = u[j];
    }
    __syncthreads();
#pragma unroll
    for (int it = 0; it < 2; ++it) {
        const int d = (tid >> 3) + it * 32;
        const int tc = (tid & 7) * 8;
        *reinterpret_cast<int4*>(Vt + base + (size_t)d * Tn + t0 + tc) =
            *reinterpret_cast<const int4*>(&Ts[d][tc]);
    }
}

// ---------------------------------------------------------------------------
// m97-style MFMA GEMM: C[M,N] = A[M,K]*Bt[N,K]^T, A/Bt bf16, fp32 accum.
// 128x128 tile, BK=64, 4 waves (64x64 quadrant each). Fragment-order LDS
// staging via global_load_lds. EPI==0: row-major store. EPI==1: QKV split.
// ---------------------------------------------------------------------------
template <int EPI>
__global__ __launch_bounds__(256) void gemm_lds(
    const unsigned short* __restrict__ A, const unsigned short* __restrict__ Bt,
    void* __restrict__ Out, unsigned short* __restrict__ Qo,
    unsigned short* __restrict__ Ko, unsigned short* __restrict__ Vo,
    int M, int N, int K, const int* __restrict__ flag)
{
    __shared__ unsigned short As[8192];   // 16 chunks x 512 elems
    __shared__ unsigned short Bs[8192];
    const int tid = threadIdx.x;
    const int w = tid >> 6, l = tid & 63;
    const int l15 = l & 15, l4 = l >> 4;
    const int rowBase = blockIdx.y * 128;
    const int colBase = blockIdx.x * 128;
    const int mq = (w & 1) * 64, nq = (w >> 1) * 64;
    const bool f32 = (*flag != 0);

    const int laneRow = l15, laneK = l4 * 8;

    f32x4 acc[4][4];
#pragma unroll
    for (int i = 0; i < 4; ++i)
#pragma unroll
        for (int j = 0; j < 4; ++j) acc[i][j] = (f32x4){0.f, 0.f, 0.f, 0.f};

    for (int k0 = 0; k0 < K; k0 += 64) {
        __syncthreads();
#pragma unroll
        for (int j = 0; j < 4; ++j) {
            const int c = w * 4 + j;
            const int mt_g = c >> 1, kh = c & 1;
            const size_t ga = (size_t)(rowBase + mt_g * 16 + laneRow) * K + k0 + kh * 32 + laneK;
            const size_t gb = (size_t)(colBase + mt_g * 16 + laneRow) * K + k0 + kh * 32 + laneK;
            async_ld16(A + ga, &As[c * 512]);
            async_ld16(Bt + gb, &Bs[c * 512]);
        }
        __syncthreads();

#pragma unroll
        for (int kh = 0; kh < 2; ++kh) {
            bf16x8 af[4], bf[4];
#pragma unroll
            for (int mt = 0; mt < 4; ++mt)
                af[mt] = *reinterpret_cast<const bf16x8*>(
                    &As[(((mq >> 4) + mt) * 2 + kh) * 512 + l * 8]);
#pragma unroll
            for (int nt = 0; nt < 4; ++nt)
                bf[nt] = *reinterpret_cast<const bf16x8*>(
                    &Bs[(((nq >> 4) + nt) * 2 + kh) * 512 + l * 8]);
#pragma unroll
            for (int mt = 0; mt < 4; ++mt)
#pragma unroll
                for (int nt = 0; nt < 4; ++nt)
                    acc[mt][nt] = __builtin_amdgcn_mfma_f32_16x16x32_bf16(af[mt], bf[nt], acc[mt][nt], 0, 0, 0);
        }
    }

#pragma unroll
    for (int mt = 0; mt < 4; ++mt)
#pragma unroll
        for (int i = 0; i < 4; ++i) {
            const int m = rowBase + mq + mt * 16 + l4 * 4 + i;
#pragma unroll
            for (int nt = 0; nt < 4; ++nt) {
                const int n0 = colBase + nq + nt * 16 + l15;
                if (EPI == 0) {
                    if (f32) ((float*)Out)[(size_t)m * N + n0] = acc[mt][nt][i];
                    else ((unsigned short*)Out)[(size_t)m * N + n0] = f2b(acc[mt][nt][i]);
                } else {
                    const int sec = n0 / 768;
                    const int cc = n0 - sec * 768;
                    const int h = cc >> 6, d = cc & 63;
                    const int b = m >> 12, t = m & 4095;
                    unsigned short* dst = (sec == 0) ? Qo : (sec == 1) ? Ko : Vo;
                    dst[(((size_t)(b * Hn + h) * Tn + t) * Dn) + d] = f2b(acc[mt][nt][i]);
                }
            }
        }
}

// ---------------------------------------------------------------------------
// Fallback QKV GEMM (verified): VGPR staging with inline fp32->bf16.
// ---------------------------------------------------------------------------
__global__ __launch_bounds__(256) void gemm_qkv_fb(
    const void* __restrict__ A, const unsigned short* __restrict__ Bt,
    unsigned short* __restrict__ Qo, unsigned short* __restrict__ Ko,
    unsigned short* __restrict__ Vo, int M, int N, int K,
    const int* __restrict__ flag)
{
    __shared__ unsigned short As[128 * PAD];
    __shared__ unsigned short Bs[128 * PAD];
    const int tid = threadIdx.x;
    const int w = tid >> 6, l = tid & 63;
    const int l15 = l & 15, l4 = l >> 4;
    const int rowBase = blockIdx.y * 128;
    const int colBase = blockIdx.x * 128;
    const int mq = (w & 1) * 64, nq = (w >> 1) * 64;
    const bool af32 = (*flag != 0);

    f32x4 acc[4][4];
#pragma unroll
    for (int i = 0; i < 4; ++i)
#pragma unroll
        for (int j = 0; j < 4; ++j) acc[i][j] = (f32x4){0.f, 0.f, 0.f, 0.f};

    for (int k0 = 0; k0 < K; k0 += 64) {
        __syncthreads();
#pragma unroll
        for (int it = 0; it < 4; ++it) {
            const int s = tid + it * 256;
            const int r = s >> 3, c = (s & 7) * 8;
            union { int4 v; unsigned short u[8]; } pk;
            if (af32) {
                const float* p = (const float*)A + (size_t)(rowBase + r) * K + k0 + c;
                float4 a = *reinterpret_cast<const float4*>(p);
                float4 b = *reinterpret_cast<const float4*>(p + 4);
                float t[8] = {a.x, a.y, a.z, a.w, b.x, b.y, b.z, b.w};
#pragma unroll
                for (int j = 0; j < 8; ++j) pk.u[j] = f2b(t[j]);
            } else {
                pk.v = *reinterpret_cast<const int4*>(
                    (const unsigned short*)A + (size_t)(rowBase + r) * K + k0 + c);
            }
            *reinterpret_cast<int4*>(&As[r * PAD + c]) = pk.v;
            *reinterpret_cast<int4*>(&Bs[r * PAD + c]) =
                *reinterpret_cast<const int4*>(Bt + (size_t)(colBase + r) * K + k0 + c);
        }
        __syncthreads();
#pragma unroll
        for (int kk = 0; kk < 64; kk += 32) {
            bf16x8 af[4], bf[4];
#pragma unroll
            for (int mt = 0; mt < 4; ++mt)
                af[mt] = *reinterpret_cast<const bf16x8*>(&As[(mq + mt * 16 + l15) * PAD + kk + l4 * 8]);
#pragma unroll
            for (int nt = 0; nt < 4; ++nt)
                bf[nt] = *reinterpret_cast<const bf16x8*>(&Bs[(nq + nt * 16 + l15) * PAD + kk + l4 * 8]);
#pragma unroll
            for (int mt = 0; mt < 4; ++mt)
#pragma unroll
                for (int nt = 0; nt < 4; ++nt)
                    acc[mt][nt] = __builtin_amdgcn_mfma_f32_16x16x32_bf16(af[mt], bf[nt], acc[mt][nt], 0, 0, 0);
        }
    }

#pragma unroll
    for (int mt = 0; mt < 4; ++mt)
#pragma unroll
        for (int i = 0; i < 4; ++i) {
            const int m = rowBase + mq + mt * 16 + l4 * 4 + i;
#pragma unroll
            for (int nt = 0; nt < 4; ++nt) {
                const int n0 = colBase + nq + nt * 16 + l15;
                const int sec = n0 / 768;
                const int cc = n0 - sec * 768;
                const int h = cc >> 6, d = cc & 63;
                const int b = m >> 12, t = m & 4095;
                unsigned short* dst = (sec == 0) ? Qo : (sec == 1) ? Ko : Vo;
                dst[(((size_t)(b * Hn + h) * Tn + t) * Dn) + d] = f2b(acc[mt][nt][i]);
            }
        }
}

// ---------------------------------------------------------------------------
// MFMA flash attention v4: v3 + register-direct PV (no Ps LDS round-trip).
//
// After swapped QK^T, lane (q=l15, l4) holds P[q][key=tt*16+l4*4+i] — which
// IS the A-fragment layout of v_mfma_f32_16x16x16_bf16 (lane: row=l15,
// k=l4*4+0..3). So PV consumes P directly from registers:
//   o[dt] += mfma_16x16x16(pa[tt], bv[dt][tt])  over tt=0..3
// with bv a ds_read_b64 B-fragment from the SAME Vs chunks already staged
// (byte addr = dt*2048 + tt*512 + lane-const; 2-way bank alias = free).
// Removes 4 ds_writes + 2 b128 reads + the write->lgkm->read latency per
// wave-stage, and the entire Ps buffer (LDS 41.2 -> 32 KB).
// Identical numerics (same cvt_pk rounding), identical C/D output layout.
// ---------------------------------------------------------------------------
__global__ __launch_bounds__(256, 4) void attn_mfma2(
    const unsigned short* __restrict__ Q, const unsigned short* __restrict__ K,
    const unsigned short* __restrict__ Vt, unsigned short* __restrict__ Y)
{
    __shared__ unsigned short Ks[2][8 * 512];   // chunk (tt,kh): 16 keys x 32 d
    __shared__ unsigned short Vs[2][8 * 512];   // chunk (dt,kh): 16 d x 32 keys

    const int tid = threadIdx.x;
    const int w = tid >> 6, l = tid & 63;    // 4 waves x 16 q-rows
    const int l15 = l & 15, l4 = l >> 4;

    // XCD-aware remap: XCD r = f%8 handles bh in [3r, 3r+3)
    const int f = (int)blockIdx.y * 32 + (int)blockIdx.x;
    const int r8 = f & 7, j = f >> 3;
    const int bh = r8 * 3 + (j >> 5);
    const int xq = j & 31;

    const size_t base = (size_t)bh * Tn * Dn;   // same size for K ([T][D]) and Vt ([D][T])
    const float sc = 0.125f * 1.44269504088896f;   // D^-0.5 * log2(e)
    const int b = bh / Hn, h = bh - b * Hn;

    // lane-constant byte offset for PV B-fragment reads (16x16x16 layout)
    const int vlb = (l4 >> 1) * 256 + l15 * 16 + (l4 & 1) * 8;

    for (int half = 0; half < 2; ++half) {
        const int t = half ? xq : (63 - xq);
        const int q0 = t * 64;
        const int qrow = q0 + w * 16 + l15;    // this lane's q (swapped layout)

        bf16x8 aq[2];
#pragma unroll
        for (int kh = 0; kh < 2; ++kh)
            aq[kh] = *reinterpret_cast<const bf16x8*>(
                Q + base + (size_t)qrow * Dn + kh * 32 + l4 * 8);

        f32x4 o[4];
#pragma unroll
        for (int dt = 0; dt < 4; ++dt) o[dt] = (f32x4){0.f, 0.f, 0.f, 0.f};
        float lsum = 0.f;

        const int nst = (q0 >> 6) + 1;   // 64-key stages this half

        // prologue: all waves done reading LDS (prev half) before overwrite
        __syncthreads();
#pragma unroll
        for (int jj = 0; jj < 2; ++jj) {     // stage tile 0 -> buf 0
            const int c = w * 2 + jj;
            const int sub = c >> 1, kh = c & 1;
            async_ld16(K + base + (size_t)(sub * 16 + l15) * Dn + kh * 32 + l4 * 8,
                       &Ks[0][c * 512]);
            async_ld16(Vt + base + (size_t)(sub * 16 + l15) * Tn + kh * 32 + l4 * 8,
                       &Vs[0][c * 512]);
        }

        int cur = 0;
        for (int s = 0; s < nst; ++s) {
            const int k0 = s << 6;
            __syncthreads();   // implicit vmcnt(0): buf[cur] complete; joins waves

            if (s + 1 < nst) {   // prefetch next tile into buf[cur^1]
                const int kn = k0 + 64;
#pragma unroll
                for (int jj = 0; jj < 2; ++jj) {
                    const int c = w * 2 + jj;
                    const int sub = c >> 1, kh = c & 1;
                    async_ld16(K + base + (size_t)(kn + sub * 16 + l15) * Dn + kh * 32 + l4 * 8,
                               &Ks[cur ^ 1][c * 512]);
                    async_ld16(Vt + base + (size_t)(sub * 16 + l15) * Tn + kn + kh * 32 + l4 * 8,
                               &Vs[cur ^ 1][c * 512]);
                }
            }

            // S^T = K Q^T: C[col=q(l15)][row=key(l4*4+i)] per key-subtile tt
            f32x4 sfr[4];
#pragma unroll
            for (int tt = 0; tt < 4; ++tt) {
                bf16x8 ak0 = *reinterpret_cast<const bf16x8*>(&Ks[cur][(tt * 2 + 0) * 512 + l * 8]);
                bf16x8 ak1 = *reinterpret_cast<const bf16x8*>(&Ks[cur][(tt * 2 + 1) * 512 + l * 8]);
                f32x4 z = (f32x4){0.f, 0.f, 0.f, 0.f};
                z = __builtin_amdgcn_mfma_f32_16x16x32_bf16(ak0, aq[0], z, 0, 0, 0);
                z = __builtin_amdgcn_mfma_f32_16x16x32_bf16(ak1, aq[1], z, 0, 0, 0);
                sfr[tt] = z;
            }

            // p = exp2(s*sc), causal mask only on the last stage
            const bool need_mask = (k0 + 63 > q0);
            float p[4][4];
#pragma unroll
            for (int tt = 0; tt < 4; ++tt)
#pragma unroll
                for (int i = 0; i < 4; ++i) {
                    float s2 = sfr[tt][i] * sc;
                    if (need_mask && (k0 + tt * 16 + l4 * 4 + i > qrow)) s2 = -1e30f;
                    const float e = exp2f(s2);
                    p[tt][i] = e;
                    lsum += e;
                }

            // pack P to bf16 A-fragments (registers only, no LDS)
            bf16x4 pa[4];
#pragma unroll
            for (int tt = 0; tt < 4; ++tt) {
                union { unsigned int u[2]; bf16x4 v; } uu;
                uu.u[0] = cvt_pk_bf16(p[tt][0], p[tt][1]);
                uu.u[1] = cvt_pk_bf16(p[tt][2], p[tt][3]);
                pa[tt] = uu.v;
            }

            // PV: o[dt] += sum_tt mfma_16x16x16(pa[tt], V-frag(dt,tt))
            const char* vb = (const char*)&Vs[cur][0];
#pragma unroll
            for (int dt = 0; dt < 4; ++dt) {
#pragma unroll
                for (int tt = 0; tt < 4; ++tt) {
                    bf16x4 bv = *reinterpret_cast<const bf16x4*>(vb + dt * 2048 + tt * 512 + vlb);
                    o[dt] = __builtin_amdgcn_mfma_f32_16x16x16bf16_1k(pa[tt], bv, o[dt], 0, 0, 0);
                }
            }
            cur ^= 1;
        }

        // reduce lsum across the 4 l4-groups sharing q=l15
        lsum += __shfl_xor(lsum, 16);
        lsum += __shfl_xor(lsum, 32);

#pragma unroll
        for (int i = 0; i < 4; ++i) {
            // output row q-local = l4*4+i; its lsum lives at lane l15 == l4*4+i
            const float lv = __shfl(lsum, (l & 48) + (l4 * 4 + i));
            const float inv = 1.0f / lv;
            const int row = q0 + w * 16 + l4 * 4 + i;
#pragma unroll
            for (int dt = 0; dt < 4; ++dt)
                Y[((size_t)(b * Tn + row)) * Cn + h * 64 + dt * 16 + l15] = f2b(o[dt][i] * inv);
        }
    }
}

// ---------------------------------------------------------------------------
// Fallback attention (round-1 verified, no V^T buffer needed).
// ---------------------------------------------------------------------------
__global__ __launch_bounds__(256, 3) void attn_mfma_fb(
    const unsigned short* __restrict__ Q, const unsigned short* __restrict__ K,
    const unsigned short* __restrict__ V, unsigned short* __restrict__ Y)
{
    __shared__ unsigned short Ks[96 * PAD];
    __shared__ unsigned short Vtl[96 * PAD];
    __shared__ unsigned short Ps[96 * PAD];

    const int tid = threadIdx.x;
    const int w = tid >> 6, l = tid & 63;
    const int l15 = l & 15, l4 = l >> 4;
    const int bh = blockIdx.y;
    const size_t base = (size_t)bh * Tn * Dn;
    const float sc = 0.125f * 1.44269504088896f;
    const int b = bh / Hn, h = bh - b * Hn;

    for (int half = 0; half < 2; ++half) {
        const int t = half ? (int)blockIdx.x : (63 - (int)blockIdx.x);
        const int q0 = t * 64;

        bf16x8 aq[2];
#pragma unroll
        for (int kh = 0; kh < 2; ++kh)
            aq[kh] = *reinterpret_cast<const bf16x8*>(
                Q + base + (size_t)(q0 + w * 16 + l15) * Dn + kh * 32 + l4 * 8);

        f32x4 o[4];
#pragma unroll
        for (int dt = 0; dt < 4; ++dt) o[dt] = (f32x4){0.f, 0.f, 0.f, 0.f};
        float l_i[4] = {0.f, 0.f, 0.f, 0.f};

        const int kend = q0 + 64;
        for (int k0 = 0; k0 < kend; k0 += 64) {
            __syncthreads();
#pragma unroll
            for (int it = 0; it < 2; ++it) {
                const int s = tid + it * 256;
                const int r = s >> 3, c = (s & 7) * 8;
                *reinterpret_cast<int4*>(&Ks[r * PAD + c]) =
                    *reinterpret_cast<const int4*>(K + base + (size_t)(k0 + r) * Dn + c);
            }
#pragma unroll
            for (int it = 0; it < 2; ++it) {
                const int r = tid & 63, d0 = (tid >> 6) * 8 + it * 32;
                int4 vv = *reinterpret_cast<const int4*>(V + base + (size_t)(k0 + r) * Dn + d0);
                const unsigned short* vu = reinterpret_cast<const unsigned short*>(&vv);
#pragma unroll
                for (int j = 0; j < 8; ++j) Vtl[(d0 + j) * PAD + r] = vu[j];
            }
            __syncthreads();

            f32x4 sfr[4];
#pragma unroll
            for (int tt = 0; tt < 4; ++tt) {
                bf16x8 bk0 = *reinterpret_cast<const bf16x8*>(&Ks[(tt * 16 + l15) * PAD + l4 * 8]);
                bf16x8 bk1 = *reinterpret_cast<const bf16x8*>(&Ks[(tt * 16 + l15) * PAD + 32 + l4 * 8]);
                f32x4 z = (f32x4){0.f, 0.f, 0.f, 0.f};
                z = __builtin_amdgcn_mfma_f32_16x16x32_bf16(aq[0], bk0, z, 0, 0, 0);
                z = __builtin_amdgcn_mfma_f32_16x16x32_bf16(aq[1], bk1, z, 0, 0, 0);
                sfr[tt] = z;
            }

            const bool need_mask = (k0 + 63 > q0);
            float p[4][4];
#pragma unroll
            for (int tt = 0; tt < 4; ++tt) {
                const int cb = k0 + tt * 16 + l15;
                const int rb = q0 + w * 16 + l4 * 4;
#pragma unroll
                for (int i = 0; i < 4; ++i) {
                    float s = sfr[tt][i] * sc;
                    if (need_mask && (cb > rb + i)) s = -1e30f;
                    const float e = exp2f(s);
                    p[tt][i] = e;
                    l_i[i] += e;
                }
            }

#pragma unroll
            for (int tt = 0; tt < 4; ++tt)
#pragma unroll
                for (int i = 0; i < 4; ++i)
                    Ps[(w * 16 + l4 * 4 + i) * PAD + tt * 16 + l15] = f2b(p[tt][i]);

            bf16x8 ap0 = *reinterpret_cast<const bf16x8*>(&Ps[(w * 16 + l15) * PAD + l4 * 8]);
            bf16x8 ap1 = *reinterpret_cast<const bf16x8*>(&Ps[(w * 16 + l15) * PAD + 32 + l4 * 8]);
#pragma unroll
            for (int dt = 0; dt < 4; ++dt) {
                bf16x8 bv0 = *reinterpret_cast<const bf16x8*>(&Vtl[(dt * 16 + l15) * PAD + l4 * 8]);
                bf16x8 bv1 = *reinterpret_cast<const bf16x8*>(&Vtl[(dt * 16 + l15) * PAD + 32 + l4 * 8]);
                o[dt] = __builtin_amdgcn_mfma_f32_16x16x32_bf16(ap0, bv0, o[dt], 0, 0, 0);
                o[dt] = __builtin_amdgcn_mfma_f32_16x16x32_bf16(ap1, bv1, o[dt], 0, 0, 0);
            }
        }

#pragma unroll
        for (int i = 0; i < 4; ++i)
#pragma unroll
            for (int off = 1; off < 16; off <<= 1) l_i[i] += __shfl_xor(l_i[i], off);

#pragma unroll
        for (int i = 0; i < 4; ++i) {
            const float inv = 1.0f / l_i[i];
            const int row = q0 + w * 16 + l4 * 4 + i;
#pragma unroll
            for (int dt = 0; dt < 4; ++dt)
                Y[((size_t)(b * Tn + row)) * Cn + h * 64 + dt * 16 + l15] = f2b(o[dt][i] * inv);
        }
    }
}

extern "C" void kernel_launch(void* const* d_in, const int* in_sizes, int n_in,
                              void* d_out, int out_size, void* d_ws, size_t ws_size,
                              hipStream_t stream)
{
    const void* x = d_in[0];
    const void* wqkv = d_in[1];
    const void* wproj = d_in[2];
    const size_t HSZ = (size_t)Bn * Hn * Tn * Dn;   // 6291456 elems
    unsigned short* q = (unsigned short*)d_ws;
    unsigned short* k = q + HSZ;
    unsigned short* v = k + HSZ;
    unsigned short* R = v + HSZ;          // wqkvT during QKV gemm, y afterwards
    unsigned short* wqkvT = R;            // [2304][768] = 1769472 elems <= HSZ
    unsigned short* y = R;
    unsigned short* wprojT = q;           // [768][768], reused after attn
    // Big layout adds xb (bf16 copy of x) at 4*HSZ; vt reuses xb after the
    // QKV gemm (both HSZ elems). Need 5*HSZ*2+16 bytes.
    const bool big = ws_size >= (size_t)5 * HSZ * 2 + 16;
    unsigned short* xb = R + HSZ;
    unsigned short* vt = xb;              // V^T [B,H,D,T], overwrites xb
    int* flag = big ? (int*)(xb + HSZ) : (int*)(R + HSZ);

    detect_k<<<1, 256, 0, stream>>>((const unsigned short*)wqkv, flag);
    transpose_w_k<<<dim3(3 * Cn / 64, Cn / 64), 256, 0, stream>>>(wqkv, wqkvT, Cn, 3 * Cn, flag);
    if (big) {
        convert_x_k<<<(Mn * Cn) / (256 * 8), 256, 0, stream>>>(x, xb, flag);
        gemm_lds<1><<<dim3(3 * Cn / 128, Mn / 128), 256, 0, stream>>>(
            xb, wqkvT, nullptr, q, k, v, Mn, 3 * Cn, Cn, flag);
        transpose_v_k<<<dim3(Tn / 64, Bn * Hn), 256, 0, stream>>>(v, vt);
        attn_mfma2<<<dim3(Tn / 128, Bn * Hn), 256, 0, stream>>>(q, k, vt, y);
    } else {
        gemm_qkv_fb<<<dim3(3 * Cn / 128, Mn / 128), 256, 0, stream>>>(
            x, wqkvT, q, k, v, Mn, 3 * Cn, Cn, flag);
        attn_mfma_fb<<<dim3(Tn / 128, Bn * Hn), 256, 0, stream>>>(q, k, v, y);
    }
    transpose_w_k<<<dim3(Cn / 64, Cn / 64), 256, 0, stream>>>(wproj, wprojT, Cn, Cn, flag);
    gemm_lds<0><<<dim3(Cn / 128, Mn / 128), 256, 0, stream>>>(
        y, wprojT, d_out, nullptr, nullptr, nullptr, Mn, Cn, Cn, flag);
}